// Round 11
// baseline (216.056 us; speedup 1.0000x reference)
//
#include <hip/hip_runtime.h>
#include <math.h>

#define SB   2
#define SEQ  2048
#define FDIM 1024
#define NH   16
#define HD   64
#define BH   (SB * NH)   // 32
#define LK   72          // attention LDS row stride in f16 elems (64 + 8 pad)

typedef _Float16 half8 __attribute__((ext_vector_type(8)));
typedef __attribute__((ext_vector_type(4))) float floatx4;
typedef __attribute__((ext_vector_type(16))) float floatx16;
typedef unsigned int uintx4 __attribute__((ext_vector_type(4)));
typedef unsigned int uint2v __attribute__((ext_vector_type(2)));

__device__ __forceinline__ unsigned pk_f16(float a, float b) {
    unsigned short ha = __builtin_bit_cast(unsigned short, (_Float16)a);
    unsigned short hb = __builtin_bit_cast(unsigned short, (_Float16)b);
    return (unsigned)ha | ((unsigned)hb << 16);
}
__device__ __forceinline__ unsigned short f16_1(float a) {
    _Float16 h = (_Float16)a;
    return __builtin_bit_cast(unsigned short, h);
}
__device__ __forceinline__ void load16_lds(const unsigned short* g, unsigned short* l) {
    __builtin_amdgcn_global_load_lds(
        (const __attribute__((address_space(1))) unsigned int*)g,
        (__attribute__((address_space(3))) unsigned int*)l, 16, 0, 0);
}
// hazard-safe permlane32_swap via builtin: swaps a.hi32lanes <-> b.lo32lanes
__device__ __forceinline__ void pl32(unsigned &a, unsigned &b) {
    uint2v r = __builtin_amdgcn_permlane32_swap(a, b, false, false);
    a = r[0]; b = r[1];
}
__device__ __forceinline__ half8 bc4(unsigned a, unsigned b, unsigned c, unsigned d) {
    uintx4 t; t[0] = a; t[1] = b; t[2] = c; t[3] = d;
    return __builtin_bit_cast(half8, t);
}
__device__ __forceinline__ floatx16 zero16() {
    floatx16 z;
    #pragma unroll
    for (int i = 0; i < 16; ++i) z[i] = 0.f;
    return z;
}

// ---------------------------------------------------------------------------
// Combined precompute: blocks [0,4096) convert activations fp32->f16;
// blocks [4096,5120) transpose+convert the three weight matrices.
// ---------------------------------------------------------------------------
__global__ __launch_bounds__(256) void cvt_all(
    const float* __restrict__ in0, const float* __restrict__ in1,
    unsigned short* __restrict__ out0, unsigned short* __restrict__ out1,
    const float* __restrict__ Wq, const float* __restrict__ Wkv,
    const float* __restrict__ Wo, unsigned short* __restrict__ Wqt,
    unsigned short* __restrict__ Wkvt, unsigned short* __restrict__ Wot)
{
    __shared__ float T[64 * 65];
    const int tid = threadIdx.x;
    int bid = blockIdx.x;

    if (bid < 4096) {               // activation convert path (no LDS use)
        const float* in = (bid < 2048) ? in0 : in1;
        unsigned short* out = (bid < 2048) ? out0 : out1;
        int i = ((bid & 2047) * 256 + tid) * 8;
        float4 a = *(const float4*)(in + i);
        float4 b = *(const float4*)(in + i + 4);
        uint4 o;
        o.x = pk_f16(a.x, a.y); o.y = pk_f16(a.z, a.w);
        o.z = pk_f16(b.x, b.y); o.w = pk_f16(b.z, b.w);
        *(uint4*)(out + i) = o;
        return;
    }

    int id = bid - 4096;            // weight transpose path
    const float* W; unsigned short* Wt; int N, n0, k0;
    if (id < 256)      { W = Wq;  Wt = Wqt;  N = 1024; n0 = (id & 15) << 6; k0 = (id >> 4) << 6; }
    else if (id < 768) { id -= 256; W = Wkv; Wt = Wkvt; N = 2048; n0 = (id & 31) << 6; k0 = (id >> 5) << 6; }
    else               { id -= 768; W = Wo;  Wt = Wot;  N = 1024; n0 = (id & 15) << 6; k0 = (id >> 4) << 6; }

    #pragma unroll
    for (int i = 0; i < 4; ++i) {
        int idx = tid + (i << 8);
        int row = idx >> 4, c4 = idx & 15;
        float4 v = *(const float4*)(W + (size_t)(k0 + row) * N + n0 + (c4 << 2));
        float* tp = &T[row * 65 + (c4 << 2)];
        tp[0] = v.x; tp[1] = v.y; tp[2] = v.z; tp[3] = v.w;
    }
    __syncthreads();
    #pragma unroll
    for (int i = 0; i < 4; ++i) {
        int idx = tid + (i << 8);
        int n = idx >> 4, c4 = idx & 15;
        float x = T[(c4 * 4 + 0) * 65 + n];
        float y = T[(c4 * 4 + 1) * 65 + n];
        float z = T[(c4 * 4 + 2) * 65 + n];
        float w = T[(c4 * 4 + 3) * 65 + n];
        uint2 o = make_uint2(pk_f16(x, y), pk_f16(z, w));
        *(uint2*)(Wt + (size_t)(n0 + n) * FDIM + k0 + (c4 << 2)) = o;
    }
}

// ---------------------------------------------------------------------------
// f16 MFMA GEMM core (r9 form): 128x128 tile, BK=32, double-buffered LDS,
// linear layout (r10's src swizzle reverted: conflicts->0 but time regressed
// — T2 regime gate: LDS reads aren't this structure's critical path).
// Used by gemm_out only.
// ---------------------------------------------------------------------------
__device__ __forceinline__ void gemm_core(
    const unsigned short* __restrict__ A, const unsigned short* __restrict__ Wt,
    int m0, int n0, int K, floatx4 (&acc)[4][4],
    unsigned short* Al, unsigned short* Bl)
{
    const int tid  = threadIdx.x;
    const int w    = tid >> 6;
    const int lane = tid & 63;
    const int q    = lane >> 4, l = lane & 15;
    const int wm = (w >> 1) * 64, wn = (w & 1) * 64;

    const int c   = (w * 2) * 64 + lane;      // this thread's chunk (it=0)
    const int c2  = c + 64;                   // it=1
    const int r0 = c >> 2,  o0 = (c & 3) * 8;
    const int r1 = c2 >> 2, o1 = (c2 & 3) * 8;

    // prologue: tile 0 -> buf 0
    load16_lds(A  + (size_t)(m0 + r0) * K + o0, Al + c * 8);
    load16_lds(Wt + (size_t)(n0 + r0) * K + o0, Bl + c * 8);
    load16_lds(A  + (size_t)(m0 + r1) * K + o1, Al + c2 * 8);
    load16_lds(Wt + (size_t)(n0 + r1) * K + o1, Bl + c2 * 8);

    int cur = 0;
    for (int k0 = 0; k0 < K; k0 += 32) {
        __syncthreads();                      // buf[cur] loaded & visible
        if (k0 + 32 < K) {                    // issue next tile -> buf[cur^1]
            int nb = (cur ^ 1) * 4096;
            load16_lds(A  + (size_t)(m0 + r0) * K + k0 + 32 + o0, Al + nb + c * 8);
            load16_lds(Wt + (size_t)(n0 + r0) * K + k0 + 32 + o0, Bl + nb + c * 8);
            load16_lds(A  + (size_t)(m0 + r1) * K + k0 + 32 + o1, Al + nb + c2 * 8);
            load16_lds(Wt + (size_t)(n0 + r1) * K + k0 + 32 + o1, Bl + nb + c2 * 8);
        }
        const unsigned short* Ac = Al + cur * 4096;
        const unsigned short* Bc = Bl + cur * 4096;

        half8 aF[4], bF[4];
        #pragma unroll
        for (int i = 0; i < 4; ++i)
            aF[i] = *(const half8*)(Ac + (wm + 16 * i + l) * 32 + 8 * q);
        #pragma unroll
        for (int j = 0; j < 4; ++j)
            bF[j] = *(const half8*)(Bc + (wn + 16 * j + l) * 32 + 8 * q);
        #pragma unroll
        for (int i = 0; i < 4; ++i)
            #pragma unroll
            for (int j = 0; j < 4; ++j)
                acc[i][j] = __builtin_amdgcn_mfma_f32_16x16x32_f16(
                    aF[i], bF[j], acc[i][j], 0, 0, 0);
        cur ^= 1;
    }
}

// ---------------------------------------------------------------------------
// Merged Q + KV projection GEMM — 3-BUFFER COUNTED-VMCNT PIPELINE (T3+T4).
// 256x256 tile, BK=32, 512 threads (8 waves, 2Mx4N), acc[8][4]/wave.
// LDS [3][256x32] per operand (96 KB): compute tile t from buf t%3 while
// tile t+1 is in flight and tile t+2 stages into buf (t+2)%3 — that buffer
// held tile t-1, fully read before the previous trailing barrier (no race).
// s_waitcnt vmcnt(8) per iter (= allow tiles t+1,t+2 in flight) — never
// drains to 0 in steady state (the m218 lever). Granule swizzle g^=(row&3)
// both-sides (source + read) makes frag ds_reads 2-way/free.
// Epilogue: Q/K head layout; V written TRANSPOSED into Vt[bh][d][z].
// Grid 192, XCD-affine: xcd owns 2 m-panels (A L2-resident), W streamed.
// ---------------------------------------------------------------------------
__global__ __launch_bounds__(512, 2) void gemm_qkv(
    const unsigned short* __restrict__ Af, const unsigned short* __restrict__ At,
    const unsigned short* __restrict__ Wqt, const unsigned short* __restrict__ Wkvt,
    const float* __restrict__ bq, const float* __restrict__ bkv,
    unsigned short* __restrict__ Qo, unsigned short* __restrict__ Ko,
    unsigned short* __restrict__ Vt)
{
    __shared__ unsigned short Ab[3 * 8192];
    __shared__ unsigned short Bb[3 * 8192];

    const int tid  = threadIdx.x;
    const int w    = tid >> 6;              // 0..7
    const int lane = tid & 63;
    const int q    = lane >> 4, l = lane & 15;
    const int wm   = (w >> 2) * 128;        // wave row base (0/128)
    const int wn   = (w & 3) * 64;          // wave col base (0..192)

    const int bid = blockIdx.x;
    const int xcd = bid & 7;
    const int idx = bid >> 3;               // 0..23
    const int by  = (idx & 1) | (xcd << 1); // 0..15
    const int bx  = idx >> 1;               // 0..11
    const int m0  = by * 256;

    const bool isQ = bx < 4;
    const unsigned short* A = isQ ? Af : At;
    const unsigned short* W = isQ ? Wqt : Wkvt;
    const float* bias       = isQ ? bq : bkv;
    const int n0 = isQ ? bx * 256 : (bx - 4) * 256;

    // staging: chunk tid -> row tid>>2 (0..127), chunk tid+512 -> +128.
    // LDS dest linear; global SOURCE granule XOR'd by row&3 (rule 21).
    const int r1 = tid >> 2;
    const int gs = ((tid & 3) ^ (r1 & 3)) * 8;   // (r1+128)&3 == r1&3
    const unsigned short* Arow1 = A + (size_t)(m0 + r1) * FDIM + gs;
    const unsigned short* Arow2 = A + (size_t)(m0 + r1 + 128) * FDIM + gs;
    const unsigned short* Wrow1 = W + (size_t)(n0 + r1) * FDIM + gs;
    const unsigned short* Wrow2 = W + (size_t)(n0 + r1 + 128) * FDIM + gs;
    const int d1 = tid * 8, d2 = (tid + 512) * 8;

#define STAGE_T(t, s) do {                                    \
    int koff = (t) * 32;                                      \
    load16_lds(Arow1 + koff, Ab + (s) * 8192 + d1);           \
    load16_lds(Arow2 + koff, Ab + (s) * 8192 + d2);           \
    load16_lds(Wrow1 + koff, Bb + (s) * 8192 + d1);           \
    load16_lds(Wrow2 + koff, Bb + (s) * 8192 + d2);           \
} while (0)

    floatx4 acc[8][4];
    #pragma unroll
    for (int i = 0; i < 8; ++i)
        #pragma unroll
        for (int j = 0; j < 4; ++j)
            acc[i][j] = (floatx4){0.f, 0.f, 0.f, 0.f};

    const int gq = (q ^ (l & 3)) * 8;       // swizzled frag granule (read side)

    STAGE_T(0, 0);
    STAGE_T(1, 1);

    int sb = 0, st2 = 2;
    for (int t = 0; t < 32; ++t) {
        if (t < 30) {
            STAGE_T(t + 2, st2);
            asm volatile("s_waitcnt vmcnt(8)");   // tile t landed (t+1,t+2 fly)
        } else if (t < 31) {
            asm volatile("s_waitcnt vmcnt(4)");   // tile 30 landed (31 flies)
        } else {
            asm volatile("s_waitcnt vmcnt(0)");   // tile 31 landed
        }
        __builtin_amdgcn_s_barrier();             // all waves: buf[sb] ready

        const unsigned short* Ac = Ab + sb * 8192;
        const unsigned short* Bc = Bb + sb * 8192;

        half8 bF[4];
        #pragma unroll
        for (int j = 0; j < 4; ++j)
            bF[j] = *(const half8*)(Bc + (wn + 16 * j + l) * 32 + gq);
        half8 aF[4];
        #pragma unroll
        for (int i = 0; i < 4; ++i)
            aF[i] = *(const half8*)(Ac + (wm + 16 * i + l) * 32 + gq);
        __builtin_amdgcn_s_setprio(1);
        #pragma unroll
        for (int i = 0; i < 4; ++i)
            #pragma unroll
            for (int j = 0; j < 4; ++j)
                acc[i][j] = __builtin_amdgcn_mfma_f32_16x16x32_f16(
                    aF[i], bF[j], acc[i][j], 0, 0, 0);
        __builtin_amdgcn_s_setprio(0);
        half8 aG[4];
        #pragma unroll
        for (int i = 0; i < 4; ++i)
            aG[i] = *(const half8*)(Ac + (wm + 64 + 16 * i + l) * 32 + gq);
        __builtin_amdgcn_s_setprio(1);
        #pragma unroll
        for (int i = 0; i < 4; ++i)
            #pragma unroll
            for (int j = 0; j < 4; ++j)
                acc[i + 4][j] = __builtin_amdgcn_mfma_f32_16x16x32_f16(
                    aG[i], bF[j], acc[i + 4][j], 0, 0, 0);
        __builtin_amdgcn_s_setprio(0);
        __builtin_amdgcn_s_barrier();             // buf[sb] fully read ->
                                                  // next iter may restage it
        sb  = (sb  == 2) ? 0 : sb  + 1;
        st2 = (st2 == 2) ? 0 : st2 + 1;
    }
#undef STAGE_T

    float bj[4];
    #pragma unroll
    for (int j = 0; j < 4; ++j) bj[j] = bias[n0 + wn + 16 * j + l];

    const int mmB = m0 + wm;
    const int b   = mmB >> 11;              // whole block in one batch
    if (isQ) {
        #pragma unroll
        for (int i = 0; i < 8; ++i) {
            int s0 = (mmB + 16 * i + 4 * q) & (SEQ - 1);
            #pragma unroll
            for (int j = 0; j < 4; ++j) {
                int n = n0 + wn + 16 * j + l;
                int h = n >> 6, dd = n & 63;
                unsigned short* qp = Qo + ((size_t)(b * NH + h) * SEQ + s0) * HD + dd;
                #pragma unroll
                for (int r = 0; r < 4; ++r) qp[r * HD] = f16_1(acc[i][j][r] + bj[j]);
            }
        }
    } else if (bx < 8) {                    // K tiles (n < 1024)
        #pragma unroll
        for (int i = 0; i < 8; ++i) {
            int s0 = (mmB + 16 * i + 4 * q) & (SEQ - 1);
            #pragma unroll
            for (int j = 0; j < 4; ++j) {
                int n = n0 + wn + 16 * j + l;
                int h = n >> 6, dd = n & 63;
                unsigned short* kp = Ko + ((size_t)(b * NH + h) * SEQ + s0) * HD + dd;
                #pragma unroll
                for (int r = 0; r < 4; ++r) kp[r * HD] = f16_1(acc[i][j][r] + bj[j]);
            }
        }
    } else {                                // V tiles -> transposed layout
        #pragma unroll
        for (int i = 0; i < 8; ++i) {
            int s0 = (mmB + 16 * i + 4 * q) & (SEQ - 1);
            #pragma unroll
            for (int j = 0; j < 4; ++j) {
                int n = n0 + wn + 16 * j + l;
                int np = n - FDIM;
                int h = np >> 6, dd = np & 63;
                uint2 o = make_uint2(pk_f16(acc[i][j][0] + bj[j], acc[i][j][1] + bj[j]),
                                     pk_f16(acc[i][j][2] + bj[j], acc[i][j][3] + bj[j]));
                *(uint2*)(Vt + ((size_t)(b * NH + h) * HD + dd) * SEQ + s0) = o;
            }
        }
    }
}

// ---------------------------------------------------------------------------
// Out-projection GEMM: fp32 output [M][N]. 1-D grid 256, XCD-affine mapping.
// ---------------------------------------------------------------------------
__global__ __launch_bounds__(256) void gemm_out(
    const unsigned short* __restrict__ A, const unsigned short* __restrict__ Wt,
    const float* __restrict__ bias, float* __restrict__ C)
{
    __shared__ unsigned short Al[2 * 128 * 32];
    __shared__ unsigned short Bl[2 * 128 * 32];

    const int tid  = threadIdx.x;
    const int w    = tid >> 6;
    const int lane = tid & 63;
    const int q    = lane >> 4, l = lane & 15;
    const int wm = (w >> 1) * 64, wn = (w & 1) * 64;

    const int bid = blockIdx.x;
    const int xcd = bid & 7;
    const int idx = bid >> 3;                 // 0..31
    const int bx  = idx >> 2;                 // 0..7 (n-tile)
    const int by  = (idx & 3) + (xcd << 2);   // 0..31 (m-tile)
    const int m0 = by * 128, n0 = bx * 128;

    floatx4 acc[4][4];
    #pragma unroll
    for (int i = 0; i < 4; ++i)
        #pragma unroll
        for (int j = 0; j < 4; ++j)
            acc[i][j] = (floatx4){0.f, 0.f, 0.f, 0.f};

    gemm_core(A, Wt, m0, n0, FDIM, acc, Al, Bl);

    float bj[4];
    #pragma unroll
    for (int j = 0; j < 4; ++j) bj[j] = bias[n0 + wn + 16 * j + l];

    #pragma unroll
    for (int i = 0; i < 4; ++i)
        #pragma unroll
        for (int j = 0; j < 4; ++j) {
            int n = n0 + wn + 16 * j + l;
            #pragma unroll
            for (int r = 0; r < 4; ++r) {
                int m = m0 + wm + 16 * i + 4 * q + r;
                C[(size_t)m * FDIM + n] = acc[i][j][r] + bj[j];
            }
        }
}

// ---------------------------------------------------------------------------
// Flash attention, swapped-operand 32x32x16 MFMA, in-register softmax (T12),
// z-SPLIT for occupancy (1024 blocks = 4 blocks/CU). Partial O + (m,l);
// merge_kernel combines.
// Block mapping: XCD affinity (same-bh blocks share bid%8) + CU balance
// (co-resident quads stage exactly 34 tiles).
// Row sums via ones-MFMA (32x32). Defer-max THR=8. T5 setprio on MFMA.
// ---------------------------------------------------------------------------
__global__ __launch_bounds__(256, 4) void attn_kernel(
    const unsigned short* __restrict__ Qg, const unsigned short* __restrict__ Kg,
    const unsigned short* __restrict__ Vtg, unsigned short* __restrict__ Op0,
    unsigned short* __restrict__ Op1, float* __restrict__ mlb)
{
    __shared__ unsigned short Kl[2][64 * LK];
    __shared__ unsigned short Vl[2][64 * LK];

    const int tid  = threadIdx.x;
    const int w    = tid >> 6;
    const int lane = tid & 63;
    const int l31  = lane & 31;
    const int hi   = lane >> 5;

    const int bid  = blockIdx.x;
    const int x    = bid & 7;               // XCD under bid%8 round-robin
    const int j2   = (bid >> 3) & 3;
    const int jj   = (bid >> 5) & 7;
    const int q2   = (bid >> 8) & 3;
    const int bh   = (j2 << 3) | x;         // same-bh blocks share an XCD
    const int st   = (q2 & 1) ? (15 - jj) : jj;
    const int half = q2 >> 1;

    const int S0  = st << 7;             // block covers s in [S0, S0+128)
    const int sw  = S0 + 32 * w;         // wave's first query row
    const int s   = sw + l31;            // this lane's query row

    const unsigned short* Qb  = Qg  + (size_t)bh * SEQ * HD;
    const unsigned short* Kb  = Kg  + (size_t)bh * SEQ * HD;
    const unsigned short* Vtb = Vtg + (size_t)bh * HD * SEQ;

    // Q as B-operand: lane holds Q[s][16*kk + 8*hi + j]
    half8 bQ[4];
    {
        const unsigned short* qp = Qb + (size_t)s * HD + 8 * hi;
        #pragma unroll
        for (int kk = 0; kk < 4; ++kk)
            bQ[kk] = *(const half8*)(qp + 16 * kk);
    }

    half8 ones;
    #pragma unroll
    for (int j = 0; j < 8; ++j) ones[j] = (_Float16)1.0f;

    float m_run = -INFINITY, l_run = 0.f;
    floatx16 oT0 = zero16(), oT1 = zero16();   // O^T accum, d in [0,32) / [32,64)

    const int ztd  = (st << 1) + (w >> 1);   // wave's diagonal z-tile
    const int ntl  = st + 1;                 // tiles in this half
    const int zb   = half ? ntl : 0;         // first z-tile of this half
    const float L2E = 1.44269504f;

    // staging addresses: thread covers K row (srow+32*it), V row (srow+32*it)
    const int srow = tid >> 3, sc8 = (tid & 7) << 3;
    half8 kreg[2], vreg[2];

    // prologue: tile zb -> buf 0
    {
        const int z0 = zb << 6;
        #pragma unroll
        for (int it = 0; it < 2; ++it) {
            kreg[it] = *(const half8*)(Kb + (size_t)(z0 + srow + 32 * it) * HD + sc8);
            vreg[it] = *(const half8*)(Vtb + (size_t)(srow + 32 * it) * SEQ + z0 + sc8);
        }
        #pragma unroll
        for (int it = 0; it < 2; ++it) {
            *(half8*)(&Kl[0][(srow + 32 * it) * LK + sc8]) = kreg[it];
            *(half8*)(&Vl[0][(srow + 32 * it) * LK + sc8]) = vreg[it];
        }
    }

    int cur = 0;
    for (int zl = 0; zl < ntl; ++zl) {
        const int zt = zb + zl;
        const bool haveNext = (zl + 1 < ntl);
        const int z0n = (zt + 1) << 6;
        __syncthreads();                 // buf[cur] writes visible

        const unsigned short* Kc = Kl[cur];
        const unsigned short* Vc = Vl[cur];

        if (zt <= ztd) {
            const int z0 = zt << 6;
            // S^T = K @ Q^T : c0 covers z' in [0,32), c1 in [32,64); col = s
            floatx16 c0 = zero16(), c1 = zero16();
            __builtin_amdgcn_s_setprio(1);
            #pragma unroll
            for (int kk = 0; kk < 4; ++kk) {
                half8 aK0 = *(const half8*)(&Kc[l31 * LK + 16 * kk + 8 * hi]);
                half8 aK1 = *(const half8*)(&Kc[(32 + l31) * LK + 16 * kk + 8 * hi]);
                c0 = __builtin_amdgcn_mfma_f32_32x32x16_f16(aK0, bQ[kk], c0, 0, 0, 0);
                c1 = __builtin_amdgcn_mfma_f32_32x32x16_f16(aK1, bQ[kk], c1, 0, 0, 0);
            }
            __builtin_amdgcn_s_setprio(0);

            // prefetch next tile (issued here so HBM latency hides under
            // softmax + PV below)
            if (haveNext) {
                #pragma unroll
                for (int it = 0; it < 2; ++it) {
                    kreg[it] = *(const half8*)(Kb + (size_t)(z0n + srow + 32 * it) * HD + sc8);
                    vreg[it] = *(const half8*)(Vtb + (size_t)(srow + 32 * it) * SEQ + z0n + sc8);
                }
            }

            if (zt == ztd) {             // diagonal tile: mask z >= s
                float mval = (s == 0) ? 0.0f : -1e12f;
                #pragma unroll
                for (int r = 0; r < 16; ++r) {
                    int zl2 = (r & 3) + 8 * (r >> 2) + 4 * hi;
                    if (z0 + zl2      >= s) c0[r] = mval;
                    if (z0 + 32 + zl2 >= s) c1[r] = mval;
                }
            }

            // row max: balanced tree + one permlane32_swap
            float pm[8];
            #pragma unroll
            for (int rr = 0; rr < 8; ++rr)
                pm[rr] = fmaxf(fmaxf(c0[2 * rr], c0[2 * rr + 1]),
                               fmaxf(c1[2 * rr], c1[2 * rr + 1]));
            float rm = fmaxf(fmaxf(fmaxf(pm[0], pm[1]), fmaxf(pm[2], pm[3])),
                             fmaxf(fmaxf(pm[4], pm[5]), fmaxf(pm[6], pm[7])));
            {
                unsigned t0 = __builtin_bit_cast(unsigned, rm);
                unsigned t1 = t0;
                pl32(t0, t1);
                rm = fmaxf(__builtin_bit_cast(float, t0), __builtin_bit_cast(float, t1));
            }

            // defer-max: only rescale when running max grows by > THR=8
            if (!__all(rm <= m_run + 8.f)) {
                float mn = fmaxf(m_run, rm);
                float alpha = __expf(m_run - mn);
                m_run = mn;
                l_run *= alpha;
                #pragma unroll
                for (int r = 0; r < 16; ++r) { oT0[r] *= alpha; oT1[r] *= alpha; }
            }

            // p = exp(S - m_run) -> packed f16 pairs
            const float mb = m_run * L2E;
            unsigned pk0[8], pk1[8];
            #pragma unroll
            for (int t = 0; t < 8; ++t) {
                float a0 = __builtin_amdgcn_exp2f(fmaf(c0[2 * t],     L2E, -mb));
                float a1 = __builtin_amdgcn_exp2f(fmaf(c0[2 * t + 1], L2E, -mb));
                float b0 = __builtin_amdgcn_exp2f(fmaf(c1[2 * t],     L2E, -mb));
                float b1 = __builtin_amdgcn_exp2f(fmaf(c1[2 * t + 1], L2E, -mb));
                pk0[t] = __builtin_bit_cast(unsigned, __builtin_amdgcn_cvt_pkrtz(a0, a1));
                pk1[t] = __builtin_bit_cast(unsigned, __builtin_amdgcn_cvt_pkrtz(b0, b1));
            }
            // redistribute across lane halves: pk regs become B-frags in place
            pl32(pk0[0], pk0[2]); pl32(pk0[1], pk0[3]);
            pl32(pk0[4], pk0[6]); pl32(pk0[5], pk0[7]);
            pl32(pk1[0], pk1[2]); pl32(pk1[1], pk1[3]);
            pl32(pk1[4], pk1[6]); pl32(pk1[5], pk1[7]);
            half8 bP[4];
            bP[0] = bc4(pk0[0], pk0[1], pk0[2], pk0[3]);   // z in [ 0,16)
            bP[1] = bc4(pk0[4], pk0[5], pk0[6], pk0[7]);   // z in [16,32)
            bP[2] = bc4(pk1[0], pk1[1], pk1[2], pk1[3]);   // z in [32,48)
            bP[3] = bc4(pk1[4], pk1[5], pk1[6], pk1[7]);   // z in [48,64)

            // O^T += V^T @ P^T ; row sums via ones-MFMA on the same frags
            floatx16 lsa = zero16();
            __builtin_amdgcn_s_setprio(1);
            #pragma unroll
            for (int kk = 0; kk < 4; ++kk) {
                half8 aV0 = *(const half8*)(&Vc[l31 * LK + 16 * kk + 8 * hi]);
                half8 aV1 = *(const half8*)(&Vc[(32 + l31) * LK + 16 * kk + 8 * hi]);
                oT0 = __builtin_amdgcn_mfma_f32_32x32x16_f16(aV0, bP[kk], oT0, 0, 0, 0);
                oT1 = __builtin_amdgcn_mfma_f32_32x32x16_f16(aV1, bP[kk], oT1, 0, 0, 0);
                lsa = __builtin_amdgcn_mfma_f32_32x32x16_f16(ones, bP[kk], lsa, 0, 0, 0);
            }
            __builtin_amdgcn_s_setprio(0);
            l_run += lsa[0];
        } else {
            // fully-masked tile for this wave: still prefetch + commit
            if (haveNext) {
                #pragma unroll
                for (int it = 0; it < 2; ++it) {
                    kreg[it] = *(const half8*)(Kb + (size_t)(z0n + srow + 32 * it) * HD + sc8);
                    vreg[it] = *(const half8*)(Vtb + (size_t)(srow + 32 * it) * SEQ + z0n + sc8);
                }
            }
        }

        if (haveNext) {
            unsigned short* Kd = Kl[cur ^ 1];
            unsigned short* Vd = Vl[cur ^ 1];
            #pragma unroll
            for (int it = 0; it < 2; ++it) {
                *(half8*)(&Kd[(srow + 32 * it) * LK + sc8]) = kreg[it];
                *(half8*)(&Vd[(srow + 32 * it) * LK + sc8]) = vreg[it];
            }
        }
        cur ^= 1;
    }

    // epilogue: partial O (pre-normalized, f16) + (m, l) f32 for merge.
    // l_run==0 (fully-masked half) -> store zeros; m_run=-inf -> weight 0.
    float inv = (l_run > 0.f) ? (1.0f / l_run) : 0.f;
    unsigned short* Oph = half ? Op1 : Op0;
    unsigned short* op = Oph + ((size_t)bh * SEQ + s) * HD + 4 * hi;
    #pragma unroll
    for (int gg = 0; gg < 4; ++gg) {
        uint2 o0 = make_uint2(pk_f16(oT0[4 * gg + 0] * inv, oT0[4 * gg + 1] * inv),
                              pk_f16(oT0[4 * gg + 2] * inv, oT0[4 * gg + 3] * inv));
        *(uint2*)(op + 8 * gg) = o0;
        uint2 o1 = make_uint2(pk_f16(oT1[4 * gg + 0] * inv, oT1[4 * gg + 1] * inv),
                              pk_f16(oT1[4 * gg + 2] * inv, oT1[4 * gg + 3] * inv));
        *(uint2*)(op + 32 + 8 * gg) = o1;
    }
    if (hi == 0) {
        float* mlp = mlb + (((size_t)half * BH + bh) * SEQ + s) * 2;
        mlp[0] = m_run; mlp[1] = l_run;
    }
}

// ---------------------------------------------------------------------------
// Merge the two z-half partials + (folded-in) row-0 path.
// Blocks [0,1024): O = (e^{m1-m}l1 O1n + e^{m2-m}l2 O2n)/(e^{m1-m}l1+e^{m2-m}l2),
//   skipping s==0. Blocks [1024,1056): row s=0 of bh = blk-1024 — uniform
//   softmax over all 2048 columns -> O = mean_z V (from Vt row sums).
// ---------------------------------------------------------------------------
__global__ __launch_bounds__(256) void merge_kernel(
    const unsigned short* __restrict__ Op0, const unsigned short* __restrict__ Op1,
    const float* __restrict__ mlb, const unsigned short* __restrict__ Vtg,
    unsigned short* __restrict__ Og)
{
    __shared__ float red[256];
    const int tid  = threadIdx.x;
    const int blk  = blockIdx.x;

    if (blk >= 1024) {                      // row-0 path
        const int bh = blk - 1024;
        const int d = tid >> 2, part = tid & 3;
        const unsigned short* vp = Vtg + ((size_t)bh * HD + d) * SEQ + part * 512;
        float sm = 0.f;
        #pragma unroll
        for (int i = 0; i < 64; ++i) {
            half8 v = *(const half8*)(vp + i * 8);
            #pragma unroll
            for (int j = 0; j < 8; ++j) sm += (float)v[j];
        }
        red[tid] = sm;
        __syncthreads();
        if (part == 0) {
            float t = red[tid] + red[tid + 1] + red[tid + 2] + red[tid + 3];
            const int b = bh >> 4, h = bh & 15;
            Og[(size_t)b * SEQ * FDIM + h * HD + d] = f16_1(t * (1.0f / 2048.0f));
        }
        return;
    }

    const int bh   = blk >> 5, band = blk & 31;
    const int r    = tid >> 2, dseg = (tid & 3) << 4;
    const int s    = (band << 6) | r;
    if (s == 0) return;                     // row-0 path handles s==0

    const size_t row = (size_t)bh * SEQ + s;
    const float* mp0 = mlb + row * 2;
    const float* mp1 = mlb + ((size_t)BH * SEQ + row) * 2;
    float m1 = mp0[0], l1 = mp0[1];
    float m2 = mp1[0], l2 = mp1[1];
    float m  = fmaxf(m1, m2);
    float w1 = __expf(m1 - m) * l1;
    float w2 = __expf(m2 - m) * l2;
    float inv = 1.0f / (w1 + w2);           // l1 > 0 for all s >= 1
    w1 *= inv; w2 *= inv;

    const unsigned short* pa = Op0 + row * HD + dseg;
    const unsigned short* pc = Op1 + row * HD + dseg;
    half8 a0 = *(const half8*)(pa), a1 = *(const half8*)(pa + 8);
    half8 c0 = *(const half8*)(pc), c1 = *(const half8*)(pc + 8);

    float f[16];
    #pragma unroll
    for (int i = 0; i < 8; ++i) {
        f[i]     = w1 * (float)a0[i] + w2 * (float)c0[i];
        f[8 + i] = w1 * (float)a1[i] + w2 * (float)c1[i];
    }
    const int b = bh >> 4, h = bh & 15;
    unsigned short* og = Og + ((size_t)b * SEQ + s) * FDIM + h * HD + dseg;
    uint4 u0, u1;
    u0.x = pk_f16(f[0],  f[1]);  u0.y = pk_f16(f[2],  f[3]);
    u0.z = pk_f16(f[4],  f[5]);  u0.w = pk_f16(f[6],  f[7]);
    u1.x = pk_f16(f[8],  f[9]);  u1.y = pk_f16(f[10], f[11]);
    u1.z = pk_f16(f[12], f[13]); u1.w = pk_f16(f[14], f[15]);
    *(uint4*)og = u0;
    *(uint4*)(og + 8) = u1;
}

// ---------------------------------------------------------------------------
extern "C" void kernel_launch(void* const* d_in, const int* in_sizes, int n_in,
                              void* d_out, int out_size, void* d_ws, size_t ws_size,
                              hipStream_t stream) {
    const float* attend_from = (const float*)d_in[0];
    const float* attend_to   = (const float*)d_in[1];
    const float* w_q   = (const float*)d_in[2];
    const float* b_q   = (const float*)d_in[3];
    const float* w_kv  = (const float*)d_in[4];
    const float* b_kv  = (const float*)d_in[5];
    const float* w_out = (const float*)d_in[6];
    const float* b_out = (const float*)d_in[7];
    float* out = (float*)d_out;

    unsigned short* ws = (unsigned short*)d_ws;
    const size_t E = (size_t)(SB * SEQ) * FDIM;   // 4M elems
    unsigned short* Af   = ws;                    // reused: attn partial O half0
    unsigned short* At   = ws + E;                //         attn partial O half1
    unsigned short* Qb   = ws + 2 * E;
    unsigned short* Kb   = ws + 3 * E;
    unsigned short* Ob   = ws + 4 * E;            // attn output (A of out-GEMM)
    unsigned short* Vt   = ws + 5 * E;            // V written transposed by gemm_qkv
    unsigned short* Wqt  = ws + 6 * E;
    unsigned short* Wkvt = ws + 6 * E + E / 4;
    unsigned short* Wot  = ws + 6 * E + E / 4 + E / 2;
    float* mlb = (float*)Wkvt;                    // reused after gemm_qkv; 1.05 MB

    cvt_all<<<dim3(5120), dim3(256), 0, stream>>>(
        attend_from, attend_to, Af, At, w_q, w_kv, w_out, Wqt, Wkvt, Wot);
    gemm_qkv<<<dim3(192), dim3(512), 0, stream>>>(
        Af, At, Wqt, Wkvt, b_q, b_kv, Qb, Kb, Vt);
    attn_kernel<<<dim3(BH * (SEQ / 128) * 2), dim3(256), 0, stream>>>(
        Qb, Kb, Vt, Af, At, mlb);
    merge_kernel<<<dim3(BH * (SEQ / 64) + BH), dim3(256), 0, stream>>>(
        Af, At, mlb, Vt, Ob);
    gemm_out<<<dim3(256), dim3(256), 0, stream>>>(Ob, Wot, b_out, out);
}